// Round 7
// baseline (77.397 us; speedup 1.0000x reference)
//
#include <hip/hip_runtime.h>
#include <math.h>

#define N_PIX 8192      // 2*64*64
#define D 64
#define HW 4096         // h*w
#define BSTRIDE 262144  // d*h*w
#define C1 14.4269504088896340736f   // 10 * log2(e); |dot| <= 1
#define NSEG 8
#define SEGCOLS (N_PIX / NSEG)       // 1024 cols per col-block
#define ITERS (SEGCOLS / 64)         // 16 iterations of 64 cols

typedef __attribute__((ext_vector_type(8))) short short8;   // 8 bf16 = 4 VGPR
typedef __attribute__((ext_vector_type(4))) float f32x4;

__device__ inline ushort f2bf(float x) {   // fp32 -> bf16 RNE
    uint u = __float_as_uint(x);
    return (ushort)((u + 0x7FFFu + ((u >> 16) & 1u)) >> 16);
}
__device__ inline float bflo(uint u) { return __uint_as_float(u << 16); }
__device__ inline float bfhi(uint u) { return __uint_as_float(u & 0xFFFF0000u); }

// B fragments for 64 cols = 4 output tiles of 16 cols, each 2 k-halves
struct B8 {
    short8 t0lo, t1lo, t2lo, t3lo;
    short8 t0hi, t1hi, t2hi, t3hi;
};
struct Acc4 { f32x4 t0, t1, t2, t3; };

__device__ inline void loadB(const ushort* p, B8& b) {
    // p points at (col_base + lrow)*D + lk*8 ; tiles at +16 cols = +16*D
    b.t0lo = *(const short8*)(p);
    b.t0hi = *(const short8*)(p + 32);
    b.t1lo = *(const short8*)(p + 16 * D);
    b.t1hi = *(const short8*)(p + 16 * D + 32);
    b.t2lo = *(const short8*)(p + 32 * D);
    b.t2hi = *(const short8*)(p + 32 * D + 32);
    b.t3lo = *(const short8*)(p + 48 * D);
    b.t3hi = *(const short8*)(p + 48 * D + 32);
}
__device__ inline void mfma8(const short8& a0, const short8& a1,
                             const B8& b, Acc4& o) {
    f32x4 z = {0.f, 0.f, 0.f, 0.f};
    o.t0 = __builtin_amdgcn_mfma_f32_16x16x32_bf16(a0, b.t0lo, z, 0, 0, 0);
    o.t1 = __builtin_amdgcn_mfma_f32_16x16x32_bf16(a0, b.t1lo, z, 0, 0, 0);
    o.t2 = __builtin_amdgcn_mfma_f32_16x16x32_bf16(a0, b.t2lo, z, 0, 0, 0);
    o.t3 = __builtin_amdgcn_mfma_f32_16x16x32_bf16(a0, b.t3lo, z, 0, 0, 0);
    o.t0 = __builtin_amdgcn_mfma_f32_16x16x32_bf16(a1, b.t0hi, o.t0, 0, 0, 0);
    o.t1 = __builtin_amdgcn_mfma_f32_16x16x32_bf16(a1, b.t1hi, o.t1, 0, 0, 0);
    o.t2 = __builtin_amdgcn_mfma_f32_16x16x32_bf16(a1, b.t2hi, o.t2, 0, 0, 0);
    o.t3 = __builtin_amdgcn_mfma_f32_16x16x32_bf16(a1, b.t3hi, o.t3, 0, 0, 0);
}
__device__ inline void expacc(const Acc4& a, float* s) {
#pragma unroll
    for (int r = 0; r < 4; ++r) {
        s[r] += __builtin_amdgcn_exp2f(fmaf(a.t0[r], C1, -C1));
        s[r] += __builtin_amdgcn_exp2f(fmaf(a.t1[r], C1, -C1));
        s[r] += __builtin_amdgcn_exp2f(fmaf(a.t2[r], C1, -C1));
        s[r] += __builtin_amdgcn_exp2f(fmaf(a.t3[r], C1, -C1));
    }
}

// ---------- K1: transpose + L2-normalize -> bf16 rows (N,64); 2 threads/pixel ----------
__global__ __launch_bounds__(256) void knorm(const float* __restrict__ z1,
                                             const float* __restrict__ z2,
                                             ushort* __restrict__ z1b,
                                             ushort* __restrict__ z2b) {
    int gid = blockIdx.x * 256 + threadIdx.x;   // 0..32767
    int half = gid & 1;
    int pixg = gid >> 1;
    int t = pixg >> 13;
    int n = pixg & (N_PIX - 1);
    const float* src = t ? z2 : z1;
    ushort* dst = t ? z2b : z1b;
    int b = n >> 12;
    int p = n & 4095;
    const float* base = src + b * BSTRIDE + (half * 32) * HW + p;
    float v[32];
    float ss = 0.f;
#pragma unroll
    for (int c = 0; c < 32; ++c) { v[c] = base[c * HW]; ss += v[c] * v[c]; }
    ss += __shfl_xor(ss, 1);
    float inv = 1.0f / fmaxf(sqrtf(ss), 1e-12f);
    uint* o = (uint*)(dst + (size_t)n * D + half * 32);
#pragma unroll
    for (int c2 = 0; c2 < 16; ++c2) {
        o[c2] = (uint)f2bf(v[2 * c2] * inv) | ((uint)f2bf(v[2 * c2 + 1] * inv) << 16);
    }
}

// ---------- K2: MFMA sim + fixed-shift exp; wave = 16 rows x 1024 cols ----------
// block = 4 waves = 64 rows; grid (128 row-blocks, 8 col-blocks) = 1024 blocks.
// One shuffle-reduce per wave; A amortized over 16 iterations.
__global__ __launch_bounds__(256) void ksim(const ushort* __restrict__ z1b,
                                            const ushort* __restrict__ z2b,
                                            float* __restrict__ ps) {
    int tid = threadIdx.x;
    int wave = tid >> 6, lane = tid & 63;
    int lrow = lane & 15;        // A-row / B-col within 16
    int lk = lane >> 4;          // k-chunk 0..3
    int rbase = blockIdx.x * 64 + wave * 16;
    int jbase = blockIdx.y * SEGCOLS;

    const ushort* ar = z1b + (size_t)(rbase + lrow) * D + lk * 8;
    short8 a0 = *(const short8*)ar;
    short8 a1 = *(const short8*)(ar + 32);

    const ushort* bbase = z2b + (size_t)(jbase + lrow) * D + lk * 8;
    const size_t ISTRIDE = (size_t)64 * D;    // 64 cols per iteration

    float s[4] = {0.f, 0.f, 0.f, 0.f};
    B8 bX, bY;
    Acc4 accP, accC;

    loadB(bbase, bX);                    // it 0
    loadB(bbase + ISTRIDE, bY);          // it 1
    mfma8(a0, a1, bX, accP);             // it 0

#pragma unroll
    for (int g = 1; g < ITERS - 1; g += 2) {
        loadB(bbase + (size_t)(g + 1) * ISTRIDE, bX);       // fetch g+1
        mfma8(a0, a1, bY, accC);                            // compute g
        expacc(accP, s);                                    // exp g-1
        if (g + 2 < ITERS) loadB(bbase + (size_t)(g + 2) * ISTRIDE, bY); // fetch g+2
        mfma8(a0, a1, bX, accP);                            // compute g+1
        expacc(accC, s);                                    // exp g
    }
    mfma8(a0, a1, bY, accC);                                // it 15
    expacc(accP, s);                                        // it 14
    expacc(accC, s);                                        // it 15

    // reduce over the 16 lanes sharing lk (different cols, same 4 rows)
#pragma unroll
    for (int off = 1; off <= 8; off <<= 1) {
#pragma unroll
        for (int r = 0; r < 4; ++r) s[r] += __shfl_xor(s[r], off);
    }
    if (lrow == 0) {
        int r0 = rbase + lk * 4;
#pragma unroll
        for (int r = 0; r < 4; ++r)
            ps[(size_t)(r0 + r) * NSEG + blockIdx.y] = s[r];
    }
}

// ---------- K3 (fused final): combine partials + diag + mean via atomic ----------
__global__ __launch_bounds__(256) void kfinal(const ushort* __restrict__ z1b,
                                              const ushort* __restrict__ z2b,
                                              const float* __restrict__ ps,
                                              float* __restrict__ out) {
    __shared__ float wsum[4];
    int tid = threadIdx.x;
    int row = blockIdx.x * 256 + tid;

    const f32x4* pp = (const f32x4*)(ps + (size_t)row * NSEG);
    float s = 0.f;
#pragma unroll
    for (int q = 0; q < NSEG / 4; ++q) {
        f32x4 v = pp[q];
        s += (v[0] + v[1]) + (v[2] + v[3]);
    }
    const uint4* xp = (const uint4*)(z1b + (size_t)row * D);
    const uint4* yp = (const uint4*)(z2b + (size_t)row * D);
    float d = 0.f;
#pragma unroll
    for (int q = 0; q < 8; ++q) {
        uint4 x = xp[q], y = yp[q];
        d = fmaf(bflo(x.x), bflo(y.x), d); d = fmaf(bfhi(x.x), bfhi(y.x), d);
        d = fmaf(bflo(x.y), bflo(y.y), d); d = fmaf(bfhi(x.y), bfhi(y.y), d);
        d = fmaf(bflo(x.z), bflo(y.z), d); d = fmaf(bfhi(x.z), bfhi(y.z), d);
        d = fmaf(bflo(x.w), bflo(y.w), d); d = fmaf(bfhi(x.w), bfhi(y.w), d);
    }
    float val = 10.0f + __logf(s) - 10.0f * d;

#pragma unroll
    for (int off = 32; off > 0; off >>= 1) val += __shfl_down(val, off);
    if ((tid & 63) == 0) wsum[tid >> 6] = val;
    __syncthreads();
    if (tid == 0) {
        float t = (wsum[0] + wsum[1]) + (wsum[2] + wsum[3]);
        atomicAdd(out, t * (1.0f / (float)N_PIX));
    }
}

extern "C" void kernel_launch(void* const* d_in, const int* in_sizes, int n_in,
                              void* d_out, int out_size, void* d_ws, size_t ws_size,
                              hipStream_t stream) {
    const float* z1 = (const float*)d_in[0];
    const float* z2 = (const float*)d_in[1];
    float* out = (float*)d_out;

    ushort* z1b = (ushort*)d_ws;                        // 1 MB
    ushort* z2b = z1b + (size_t)N_PIX * D;              // 1 MB
    float* ps   = (float*)(z2b + (size_t)N_PIX * D);    // 8192*8*4 = 256 KB

    hipMemsetAsync(out, 0, sizeof(float), stream);
    knorm<<<128, 256, 0, stream>>>(z1, z2, z1b, z2b);
    dim3 g2(N_PIX / 64, NSEG);                          // (128, 8) = 1024 blocks
    ksim<<<g2, 256, 0, stream>>>(z1b, z2b, ps);
    kfinal<<<N_PIX / 256, 256, 0, stream>>>(z1b, z2b, ps, out);
}

// Round 8
// 35.268 us; speedup vs baseline: 2.1945x; 2.1945x over previous
//
#include <hip/hip_runtime.h>
#include <math.h>

#define N_PIX 8192      // 2*64*64
#define D 64
#define HW 4096         // h*w
#define BSTRIDE 262144  // d*h*w
#define C1 14.4269504088896340736f   // 10 * log2(e); |dot| <= 1
#define NSEG 16
#define SEGCOLS (N_PIX / NSEG)       // 512 cols per col-segment
#define BC 64                        // cols per K-step (LDS tile)
#define STEPS (SEGCOLS / BC)         // 8

typedef __attribute__((ext_vector_type(8))) short short8;   // 8 bf16 = 4 VGPR
typedef __attribute__((ext_vector_type(4))) float f32x4;

#define LDS_AS __attribute__((address_space(3)))
#define GLB_AS __attribute__((address_space(1)))

__device__ inline ushort f2bf(float x) {   // fp32 -> bf16 RNE
    uint u = __float_as_uint(x);
    return (ushort)((u + 0x7FFFu + ((u >> 16) & 1u)) >> 16);
}
__device__ inline float bflo(uint u) { return __uint_as_float(u << 16); }
__device__ inline float bfhi(uint u) { return __uint_as_float(u & 0xFFFF0000u); }

// async 16B global->LDS (dest = wave-uniform base + lane*16)
__device__ inline void gll16(const ushort* g, ushort* l) {
    __builtin_amdgcn_global_load_lds((const GLB_AS uint*)g, (LDS_AS uint*)l, 16, 0, 0);
}

// Stage one 64-col x 64-ch bf16 tile (8KB) into ldsbuf, XOR-swizzled.
// Physical LDS slot p holds logical byte  col*128 + (off ^ ((col&7)<<4)).
// Wave w stages chunks c=2w,2w+1; chunk c = cols c*8..c*8+7 (1KB each).
__device__ inline void stage(const ushort* __restrict__ z2b, int jcol,
                             ushort* ldsbuf, int wave, int lane) {
    int l3 = lane >> 3, l7 = lane & 7;
    int xo = (l7 ^ l3) << 3;     // ushort offset of swizzled 16B slot
#pragma unroll
    for (int q = 0; q < 2; ++q) {
        int c = wave * 2 + q;
        const ushort* src = z2b + (size_t)(jcol + c * 8 + l3) * D + xo;
        gll16(src, ldsbuf + c * 512);
    }
}

// ---------- K1: transpose + L2-normalize -> bf16 rows (N,64); 2 threads/pixel ----------
__global__ __launch_bounds__(256) void knorm(const float* __restrict__ z1,
                                             const float* __restrict__ z2,
                                             ushort* __restrict__ z1b,
                                             ushort* __restrict__ z2b) {
    int gid = blockIdx.x * 256 + threadIdx.x;   // 0..32767
    int half = gid & 1;
    int pixg = gid >> 1;
    int t = pixg >> 13;
    int n = pixg & (N_PIX - 1);
    const float* src = t ? z2 : z1;
    ushort* dst = t ? z2b : z1b;
    int b = n >> 12;
    int p = n & 4095;
    const float* base = src + b * BSTRIDE + (half * 32) * HW + p;
    float v[32];
    float ss = 0.f;
#pragma unroll
    for (int c = 0; c < 32; ++c) { v[c] = base[c * HW]; ss += v[c] * v[c]; }
    ss += __shfl_xor(ss, 1);
    float inv = 1.0f / fmaxf(sqrtf(ss), 1e-12f);
    uint* o = (uint*)(dst + (size_t)n * D + half * 32);
#pragma unroll
    for (int c2 = 0; c2 < 16; ++c2) {
        o[c2] = (uint)f2bf(v[2 * c2] * inv) | ((uint)f2bf(v[2 * c2 + 1] * inv) << 16);
    }
}

// ---------- K2: MFMA sim + fixed-shift exp; LDS double-buffered B ----------
// block = 4 waves x 32 rows = 128 rows; 8 K-steps of 64 cols (segment 512 cols).
// grid (64, 16) = 1024 blocks.
__global__ __launch_bounds__(256) void ksim(const ushort* __restrict__ z1b,
                                            const ushort* __restrict__ z2b,
                                            float* __restrict__ ps) {
    __shared__ ushort lds[2][BC * D];   // 2 x 8KB
    int tid = threadIdx.x;
    int wave = tid >> 6, lane = tid & 63;
    int lrow = lane & 15;        // A-row / B-col within 16
    int lk = lane >> 4;          // k-chunk 0..3
    int rbase = blockIdx.x * 128 + wave * 32;
    int jbase = blockIdx.y * SEGCOLS;

    // A fragments: 2 row-tiles x 2 k-halves (fixed all kernel)
    const ushort* ar = z1b + (size_t)(rbase + lrow) * D + lk * 8;
    short8 a00 = *(const short8*)ar;
    short8 a01 = *(const short8*)(ar + 32);
    short8 a10 = *(const short8*)(ar + 16 * D);
    short8 a11 = *(const short8*)(ar + 16 * D + 32);

    float s0[4] = {0.f, 0.f, 0.f, 0.f};
    float s1[4] = {0.f, 0.f, 0.f, 0.f};

    ushort* l0 = &lds[0][0];
    ushort* l1 = &lds[1][0];

    stage(z2b, jbase, l0, wave, lane);
    __syncthreads();                         // vmcnt(0)+lgkmcnt(0)+barrier

#pragma unroll 2
    for (int t = 0; t < STEPS; ++t) {
        ushort* cur = (t & 1) ? l1 : l0;
        ushort* nxt = (t & 1) ? l0 : l1;
        if (t + 1 < STEPS) stage(z2b, jbase + (t + 1) * BC, nxt, wave, lane);

        const char* bb = (const char*)cur;
        int sw = (lrow & 7);
        f32x4 z = {0.f, 0.f, 0.f, 0.f};
        f32x4 acc0[4], acc1[4];
#pragma unroll
        for (int ct = 0; ct < 4; ++ct) {
            int rowoff = (ct * 16 + lrow) << 7;
            short8 blo = *(const short8*)(bb + rowoff + ((lk ^ sw) << 4));
            short8 bhi = *(const short8*)(bb + rowoff + (((4 + lk) ^ sw) << 4));
            acc0[ct] = __builtin_amdgcn_mfma_f32_16x16x32_bf16(a00, blo, z, 0, 0, 0);
            acc1[ct] = __builtin_amdgcn_mfma_f32_16x16x32_bf16(a10, blo, z, 0, 0, 0);
            acc0[ct] = __builtin_amdgcn_mfma_f32_16x16x32_bf16(a01, bhi, acc0[ct], 0, 0, 0);
            acc1[ct] = __builtin_amdgcn_mfma_f32_16x16x32_bf16(a11, bhi, acc1[ct], 0, 0, 0);
        }
#pragma unroll
        for (int ct = 0; ct < 4; ++ct) {
#pragma unroll
            for (int r = 0; r < 4; ++r) {
                s0[r] += __builtin_amdgcn_exp2f(fmaf(acc0[ct][r], C1, -C1));
                s1[r] += __builtin_amdgcn_exp2f(fmaf(acc1[ct][r], C1, -C1));
            }
        }
        if (t + 1 < STEPS) __syncthreads();  // staged tile complete + reads done
    }

    // reduce over 16 lanes sharing lk (different cols, same rows)
#pragma unroll
    for (int off = 1; off <= 8; off <<= 1) {
#pragma unroll
        for (int r = 0; r < 4; ++r) {
            s0[r] += __shfl_xor(s0[r], off);
            s1[r] += __shfl_xor(s1[r], off);
        }
    }
    if (lrow == 0) {
        int seg = blockIdx.y;
        int r0 = rbase + lk * 4;
#pragma unroll
        for (int r = 0; r < 4; ++r) {
            ps[(size_t)(r0 + r) * NSEG + seg] = s0[r];
            ps[(size_t)(r0 + 16 + r) * NSEG + seg] = s1[r];
        }
    }
}

// ---------- K3 (fused final): combine partials + diag + mean via atomic ----------
__global__ __launch_bounds__(256) void kfinal(const ushort* __restrict__ z1b,
                                              const ushort* __restrict__ z2b,
                                              const float* __restrict__ ps,
                                              float* __restrict__ out) {
    __shared__ float wsum[4];
    int tid = threadIdx.x;
    int row = blockIdx.x * 256 + tid;

    const f32x4* pp = (const f32x4*)(ps + (size_t)row * NSEG);
    float s = 0.f;
#pragma unroll
    for (int q = 0; q < NSEG / 4; ++q) {
        f32x4 v = pp[q];
        s += (v[0] + v[1]) + (v[2] + v[3]);
    }
    const uint4* xp = (const uint4*)(z1b + (size_t)row * D);
    const uint4* yp = (const uint4*)(z2b + (size_t)row * D);
    float d = 0.f;
#pragma unroll
    for (int q = 0; q < 8; ++q) {
        uint4 x = xp[q], y = yp[q];
        d = fmaf(bflo(x.x), bflo(y.x), d); d = fmaf(bfhi(x.x), bfhi(y.x), d);
        d = fmaf(bflo(x.y), bflo(y.y), d); d = fmaf(bfhi(x.y), bfhi(y.y), d);
        d = fmaf(bflo(x.z), bflo(y.z), d); d = fmaf(bfhi(x.z), bfhi(y.z), d);
        d = fmaf(bflo(x.w), bflo(y.w), d); d = fmaf(bfhi(x.w), bfhi(y.w), d);
    }
    float val = 10.0f + __logf(s) - 10.0f * d;

#pragma unroll
    for (int off = 32; off > 0; off >>= 1) val += __shfl_down(val, off);
    if ((tid & 63) == 0) wsum[tid >> 6] = val;
    __syncthreads();
    if (tid == 0) {
        float t = (wsum[0] + wsum[1]) + (wsum[2] + wsum[3]);
        atomicAdd(out, t * (1.0f / (float)N_PIX));
    }
}

extern "C" void kernel_launch(void* const* d_in, const int* in_sizes, int n_in,
                              void* d_out, int out_size, void* d_ws, size_t ws_size,
                              hipStream_t stream) {
    const float* z1 = (const float*)d_in[0];
    const float* z2 = (const float*)d_in[1];
    float* out = (float*)d_out;

    ushort* z1b = (ushort*)d_ws;                        // 1 MB
    ushort* z2b = z1b + (size_t)N_PIX * D;              // 1 MB
    float* ps   = (float*)(z2b + (size_t)N_PIX * D);    // 8192*16*4 = 512 KB

    hipMemsetAsync(out, 0, sizeof(float), stream);
    knorm<<<128, 256, 0, stream>>>(z1, z2, z1b, z2b);
    dim3 g2(N_PIX / 128, NSEG);                         // (64, 16) = 1024 blocks
    ksim<<<g2, 256, 0, stream>>>(z1b, z2b, ps);
    kfinal<<<N_PIX / 256, 256, 0, stream>>>(z1b, z2b, ps, out);
}

// Round 9
// 29.178 us; speedup vs baseline: 2.6526x; 1.2088x over previous
//
#include <hip/hip_runtime.h>
#include <math.h>

#define N_PIX 8192      // 2*64*64
#define D 64
#define HW 4096         // h*w
#define BSTRIDE 262144  // d*h*w
#define C1 14.4269504088896340736f   // 10 * log2(e); |dot| <= 1
#define NSEG 16
#define SEGCOLS (N_PIX / NSEG)       // 512 cols per col-segment
#define BC 128                       // cols per K-step (LDS tile 16KB)
#define STEPS (SEGCOLS / BC)         // 4

typedef __attribute__((ext_vector_type(8))) short short8;   // 8 bf16 = 4 VGPR
typedef __attribute__((ext_vector_type(4))) float f32x4;

#define LDS_AS __attribute__((address_space(3)))
#define GLB_AS __attribute__((address_space(1)))

__device__ inline ushort f2bf(float x) {   // fp32 -> bf16 RNE
    uint u = __float_as_uint(x);
    return (ushort)((u + 0x7FFFu + ((u >> 16) & 1u)) >> 16);
}
__device__ inline float bflo(uint u) { return __uint_as_float(u << 16); }
__device__ inline float bfhi(uint u) { return __uint_as_float(u & 0xFFFF0000u); }

// async 16B global->LDS (dest = wave-uniform base + lane*16)
__device__ inline void gll16(const ushort* g, ushort* l) {
    __builtin_amdgcn_global_load_lds((const GLB_AS uint*)g, (LDS_AS uint*)l, 16, 0, 0);
}

// Stage one BC-col x 64-ch bf16 tile (BC*128B) into ldsbuf, XOR-swizzled.
// Physical slot: col*128 + (off16 ^ ((col&7)<<4)).  Chunk c = cols c*8..c*8+7 (1KB).
// 4 waves stage BC/8 chunks: wave w takes c = w*(BC/32)+q.
__device__ inline void stage(const ushort* __restrict__ z2b, int jcol,
                             ushort* ldsbuf, int wave, int lane) {
    int l3 = lane >> 3, l7 = lane & 7;
    int xo = (l7 ^ l3) << 3;     // ushort offset of swizzled 16B slot
#pragma unroll
    for (int q = 0; q < BC / 32; ++q) {
        int c = wave * (BC / 32) + q;
        const ushort* src = z2b + (size_t)(jcol + c * 8 + l3) * D + xo;
        gll16(src, ldsbuf + c * 512);
    }
}

// ---------- K1: transpose + L2-normalize -> bf16 rows (N,64); 4 threads/pixel ----------
__global__ __launch_bounds__(256) void knorm(const float* __restrict__ z1,
                                             const float* __restrict__ z2,
                                             ushort* __restrict__ z1b,
                                             ushort* __restrict__ z2b,
                                             float* __restrict__ out) {
    int gid = blockIdx.x * 256 + threadIdx.x;   // 0..65535
    if (gid == 0) out[0] = 0.f;                 // fold memset (knorm precedes kfinal)
    int q = gid & 3;                             // channel quarter
    int pixg = gid >> 2;                         // 0..16383
    int t = pixg >> 13;
    int n = pixg & (N_PIX - 1);
    const float* src = t ? z2 : z1;
    ushort* dst = t ? z2b : z1b;
    int b = n >> 12;
    int p = n & 4095;
    const float* base = src + b * BSTRIDE + (q * 16) * HW + p;
    float v[16];
    float ss = 0.f;
#pragma unroll
    for (int c = 0; c < 16; ++c) { v[c] = base[c * HW]; ss += v[c] * v[c]; }
    ss += __shfl_xor(ss, 1);                     // 4-lane group shares pixel
    ss += __shfl_xor(ss, 2);
    float inv = 1.0f / fmaxf(sqrtf(ss), 1e-12f);
    uint4 w0, w1;
    uint* wp = (uint*)&w0;
#pragma unroll
    for (int c2 = 0; c2 < 8; ++c2) {
        uint val = (uint)f2bf(v[2 * c2] * inv) | ((uint)f2bf(v[2 * c2 + 1] * inv) << 16);
        if (c2 < 4) ((uint*)&w0)[c2] = val; else ((uint*)&w1)[c2 - 4] = val;
    }
    (void)wp;
    uint4* o = (uint4*)(dst + (size_t)n * D + q * 16);
    o[0] = w0;
    o[1] = w1;
}

// ---------- K2: MFMA sim + fixed-shift exp; LDS double-buffered B ----------
// block = 4 waves x 32 rows = 128 rows; 4 K-steps of 128 cols (segment 512 cols).
// grid (64, 16) = 1024 blocks = 4 blocks/CU.
__global__ __launch_bounds__(256) void ksim(const ushort* __restrict__ z1b,
                                            const ushort* __restrict__ z2b,
                                            float* __restrict__ ps) {
    __shared__ ushort lds[2][BC * D];   // 2 x 16KB
    int tid = threadIdx.x;
    int wave = tid >> 6, lane = tid & 63;
    int lrow = lane & 15;        // A-row / B-col within 16
    int lk = lane >> 4;          // k-chunk 0..3
    int rbase = blockIdx.x * 128 + wave * 32;
    int jbase = blockIdx.y * SEGCOLS;

    // A fragments: 2 row-tiles x 2 k-halves (fixed all kernel)
    const ushort* ar = z1b + (size_t)(rbase + lrow) * D + lk * 8;
    short8 a00 = *(const short8*)ar;
    short8 a01 = *(const short8*)(ar + 32);
    short8 a10 = *(const short8*)(ar + 16 * D);
    short8 a11 = *(const short8*)(ar + 16 * D + 32);

    float s0[4] = {0.f, 0.f, 0.f, 0.f};
    float s1[4] = {0.f, 0.f, 0.f, 0.f};

    ushort* l0 = &lds[0][0];
    ushort* l1 = &lds[1][0];

    stage(z2b, jbase, l0, wave, lane);
    __syncthreads();                         // vmcnt(0)+lgkmcnt(0)+barrier

#pragma unroll
    for (int t = 0; t < STEPS; ++t) {
        ushort* cur = (t & 1) ? l1 : l0;
        ushort* nxt = (t & 1) ? l0 : l1;
        if (t + 1 < STEPS) stage(z2b, jbase + (t + 1) * BC, nxt, wave, lane);

        const char* bb = (const char*)cur;
        int sw = (lrow & 7);
        f32x4 z = {0.f, 0.f, 0.f, 0.f};
#pragma unroll
        for (int ct = 0; ct < BC / 16; ++ct) {
            int rowoff = (ct * 16 + lrow) << 7;
            short8 blo = *(const short8*)(bb + rowoff + ((lk ^ sw) << 4));
            short8 bhi = *(const short8*)(bb + rowoff + (((4 + lk) ^ sw) << 4));
            f32x4 acc0 = __builtin_amdgcn_mfma_f32_16x16x32_bf16(a00, blo, z, 0, 0, 0);
            f32x4 acc1 = __builtin_amdgcn_mfma_f32_16x16x32_bf16(a10, blo, z, 0, 0, 0);
            acc0 = __builtin_amdgcn_mfma_f32_16x16x32_bf16(a01, bhi, acc0, 0, 0, 0);
            acc1 = __builtin_amdgcn_mfma_f32_16x16x32_bf16(a11, bhi, acc1, 0, 0, 0);
#pragma unroll
            for (int r = 0; r < 4; ++r) {
                s0[r] += __builtin_amdgcn_exp2f(fmaf(acc0[r], C1, -C1));
                s1[r] += __builtin_amdgcn_exp2f(fmaf(acc1[r], C1, -C1));
            }
        }
        if (t + 1 < STEPS) __syncthreads();  // staged tile complete + reads done
    }

    // reduce over 16 lanes sharing lk (different cols, same rows)
#pragma unroll
    for (int off = 1; off <= 8; off <<= 1) {
#pragma unroll
        for (int r = 0; r < 4; ++r) {
            s0[r] += __shfl_xor(s0[r], off);
            s1[r] += __shfl_xor(s1[r], off);
        }
    }
    if (lrow == 0) {
        int seg = blockIdx.y;
        int r0 = rbase + lk * 4;
#pragma unroll
        for (int r = 0; r < 4; ++r) {
            ps[(size_t)(r0 + r) * NSEG + seg] = s0[r];
            ps[(size_t)(r0 + 16 + r) * NSEG + seg] = s1[r];
        }
    }
}

// ---------- K3 (fused final): combine partials + diag + mean via atomic ----------
__global__ __launch_bounds__(256) void kfinal(const ushort* __restrict__ z1b,
                                              const ushort* __restrict__ z2b,
                                              const float* __restrict__ ps,
                                              float* __restrict__ out) {
    __shared__ float wsum[4];
    int tid = threadIdx.x;
    int row = blockIdx.x * 256 + tid;

    const f32x4* pp = (const f32x4*)(ps + (size_t)row * NSEG);
    float s = 0.f;
#pragma unroll
    for (int q = 0; q < NSEG / 4; ++q) {
        f32x4 v = pp[q];
        s += (v[0] + v[1]) + (v[2] + v[3]);
    }
    const uint4* xp = (const uint4*)(z1b + (size_t)row * D);
    const uint4* yp = (const uint4*)(z2b + (size_t)row * D);
    float d = 0.f;
#pragma unroll
    for (int q = 0; q < 8; ++q) {
        uint4 x = xp[q], y = yp[q];
        d = fmaf(bflo(x.x), bflo(y.x), d); d = fmaf(bfhi(x.x), bfhi(y.x), d);
        d = fmaf(bflo(x.y), bflo(y.y), d); d = fmaf(bfhi(x.y), bfhi(y.y), d);
        d = fmaf(bflo(x.z), bflo(y.z), d); d = fmaf(bfhi(x.z), bfhi(y.z), d);
        d = fmaf(bflo(x.w), bflo(y.w), d); d = fmaf(bfhi(x.w), bfhi(y.w), d);
    }
    float val = 10.0f + __logf(s) - 10.0f * d;

#pragma unroll
    for (int off = 32; off > 0; off >>= 1) val += __shfl_down(val, off);
    if ((tid & 63) == 0) wsum[tid >> 6] = val;
    __syncthreads();
    if (tid == 0) {
        float t = (wsum[0] + wsum[1]) + (wsum[2] + wsum[3]);
        atomicAdd(out, t * (1.0f / (float)N_PIX));
    }
}

extern "C" void kernel_launch(void* const* d_in, const int* in_sizes, int n_in,
                              void* d_out, int out_size, void* d_ws, size_t ws_size,
                              hipStream_t stream) {
    const float* z1 = (const float*)d_in[0];
    const float* z2 = (const float*)d_in[1];
    float* out = (float*)d_out;

    ushort* z1b = (ushort*)d_ws;                        // 1 MB
    ushort* z2b = z1b + (size_t)N_PIX * D;              // 1 MB
    float* ps   = (float*)(z2b + (size_t)N_PIX * D);    // 8192*16*4 = 512 KB

    knorm<<<256, 256, 0, stream>>>(z1, z2, z1b, z2b, out);
    dim3 g2(N_PIX / 128, NSEG);                         // (64, 16) = 1024 blocks
    ksim<<<g2, 256, 0, stream>>>(z1b, z2b, ps);
    kfinal<<<N_PIX / 256, 256, 0, stream>>>(z1b, z2b, ps, out);
}